// Round 11
// baseline (386.266 us; speedup 1.0000x reference)
//
#include <hip/hip_runtime.h>
#include <math.h>

// ---- types ----------------------------------------------------------------
typedef __attribute__((ext_vector_type(8))) __bf16 bf16x8;   // MFMA A/B frag (4 VGPR)
typedef __attribute__((ext_vector_type(8))) short  short8;   // raw 16B store
typedef __attribute__((ext_vector_type(4))) short  short4v;  // raw 8B store
typedef __attribute__((ext_vector_type(4))) unsigned short ushort4v;
typedef __attribute__((ext_vector_type(4))) float  floatx4;  // 16x16 C/D frag

typedef __attribute__((address_space(1))) unsigned int as1_u32;
typedef __attribute__((address_space(3))) unsigned int as3_u32;

// async global->LDS, 16B per lane, dest = uniform base + lane*16
__device__ __forceinline__ void async_copy16(const void* g, void* l) {
  __builtin_amdgcn_global_load_lds((const as1_u32*)g, (as3_u32*)l, 16, 0, 0);
}

__device__ __forceinline__ unsigned short f2bf(float f) {  // RNE float->bf16 bits
  union { float f; unsigned u; } v; v.f = f;
  unsigned r = v.u + 0x7fffu + ((v.u >> 16) & 1u);
  return (unsigned short)(r >> 16);
}

__device__ __forceinline__ floatx4 mfma_bf16(bf16x8 a, bf16x8 b, floatx4 c) {
  return __builtin_amdgcn_mfma_f32_16x16x32_bf16(a, b, c, 0, 0, 0);
}

__device__ __forceinline__ bf16x8 lds_frag(const unsigned short* p) {
  return *(const bf16x8*)(const void*)p;  // ds_read_b128
}

// ---- prep: all four f32->bf16 conversions in ONE launch --------------------
__global__ __launch_bounds__(256)
void prep(const float* __restrict__ x,  const float* __restrict__ wq,
          const float* __restrict__ wk, const float* __restrict__ wv,
          unsigned short* __restrict__ Xb, unsigned short* __restrict__ Wqb,
          unsigned short* __restrict__ Wkb, unsigned short* __restrict__ Wvb) {
  const int i = blockIdx.x * 256 + threadIdx.x;
  const float* s; unsigned short* d; int off;
  if (i < 2097152)             { s = x;  d = Xb;  off = i; }
  else if (i < 2097152+65536)  { s = wq; d = Wqb; off = i - 2097152; }
  else if (i < 2097152+131072) { s = wk; d = Wkb; off = i - (2097152+65536); }
  else                         { s = wv; d = Wvb; off = i - (2097152+131072); }
  const float4 v = ((const float4*)s)[off];
  ushort4v o;
  o.x = f2bf(v.x); o.y = f2bf(v.y); o.z = f2bf(v.z); o.w = f2bf(v.w);
  *(ushort4v*)(void*)(d + (size_t)off * 4) = o;
}

// ---- fused QKV GEMM: unchanged (verified) ----------------------------------
__global__ __launch_bounds__(256, 2)
void gemm_qkv(const unsigned short* __restrict__ Xb,
              const unsigned short* __restrict__ Wqb,
              const unsigned short* __restrict__ Wkb,
              const unsigned short* __restrict__ Wvb,
              unsigned short* __restrict__ Q,
              unsigned short* __restrict__ K,
              unsigned short* __restrict__ Vt) {
  const int gid = blockIdx.x;
  const unsigned short *A, *B; unsigned short* C;
  int m0, n0, N;
  if (gid < 512) {                        // Q = Xb · Wq^T
    A = Xb; B = Wqb; C = Q; N = 512;
    m0 = (gid & 127) * 128; n0 = (gid >> 7) * 128;
  } else if (gid < 1024) {                // K = Xb · Wk^T
    A = Xb; B = Wkb; C = K; N = 512;
    m0 = ((gid - 512) & 127) * 128; n0 = ((gid - 512) >> 7) * 128;
  } else {                                // V^T = Wv · Xb^T  (M=512, N=16384)
    A = Wvb; B = Xb; C = Vt; N = 16384;
    m0 = ((gid - 1024) & 3) * 128; n0 = ((gid - 1024) >> 2) * 128;
  }

  __shared__ unsigned short As[128 * 64];
  __shared__ unsigned short Bs[128 * 64];
  const int tid = threadIdx.x;
  const int w = tid >> 6, lane = tid & 63;
  const int quad = lane >> 4, l15 = lane & 15;
  const int wm = w >> 1, wn = w & 1;
  const int row_l = lane >> 3;
  const int chk   = lane & 7;
  const int s_chk = chk ^ row_l;          // swizzled SOURCE chunk

  floatx4 acc[16];
#pragma unroll
  for (int i = 0; i < 16; i++) acc[i] = (floatx4){0.f, 0.f, 0.f, 0.f};

  for (int kt = 0; kt < 8; kt++) {
    __syncthreads();
#pragma unroll
    for (int i = 0; i < 4; i++) {
      const int c = w * 4 + i;
      const int row = c * 8 + row_l;
      async_copy16(A + (size_t)(m0 + row) * 512 + kt * 64 + s_chk * 8, &As[c * 512]);
      async_copy16(B + (size_t)(n0 + row) * 512 + kt * 64 + s_chk * 8, &Bs[c * 512]);
    }
    __syncthreads();
#pragma unroll
    for (int kc = 0; kc < 2; kc++) {
      bf16x8 af[4], bfv[4];
#pragma unroll
      for (int i = 0; i < 4; i++) {
        const int pc = ((kc * 4 + quad) ^ (l15 & 7)) * 8;
        af[i]  = lds_frag(&As[(wm * 64 + i * 16 + l15) * 64 + pc]);
        bfv[i] = lds_frag(&Bs[(wn * 64 + i * 16 + l15) * 64 + pc]);
      }
#pragma unroll
      for (int mi = 0; mi < 4; mi++)
#pragma unroll
        for (int ni = 0; ni < 4; ni++)
          acc[mi * 4 + ni] = mfma_bf16(af[mi], bfv[ni], acc[mi * 4 + ni]);
    }
  }
#pragma unroll
  for (int mi = 0; mi < 4; mi++)
#pragma unroll
    for (int ni = 0; ni < 4; ni++)
#pragma unroll
      for (int r = 0; r < 4; r++) {
        const int row = m0 + wm * 64 + mi * 16 + quad * 4 + r;
        const int col = n0 + wn * 64 + ni * 16 + l15;
        C[(size_t)row * N + col] = f2bf(acc[mi * 4 + ni][r]);
      }
}

// ---- fused attention: 2 blocks/CU for cross-block latency hiding (round 11
// = round 10, resubmitted after infra timeout; kernel never ran) -------------
// R4 (16x16, 4 barriers) and R9 (32x32 split-K, 5 barriers) both plateau at
// ~9000 cyc/step with 1 block/CU: the serial chain QK^T->Sx->softmax->Pb->PV
// + barrier/drain stalls idles the CU ~50% of cycles (MfmaUtil 24 + VALUBusy
// 25). Fix: halve the block (256 thr / 4 waves, QBLK=32, KVBLK=32, ~70.5 KB
// LDS) -> 2 INDEPENDENT blocks/CU; one block's barrier/softmax stalls are
// filled by the other's MFMA. All index patterns are verified ancestors:
//   phase 1: one 16x16 S-tile/wave, full K=512, 16 MFMA (R4 bit-verified
//            shape; no split-K, no combine barrier -> 4 barriers/step)
//   phase 3: 16 16x16 O-tiles/wave, K=32 -> 1 MFMA each (R4 shape)
//   Ks swizzle: phys chunk = logical ^ (row&7)   (R9-verified, 64 chunks)
//   Vs/Pb swizzle: phys = logical ^ (row&3)      (same family, 4 chunks/row,
//            bank-checked: <=2-way aliasing = free)
//   DMA: explicit vmcnt(0)+sched_barrier before each publishing barrier
//        (R4-verified); V flies under phase1+softmax, K under phase3.
#define SCALE 0.044194173824159216f  // 1/sqrt(512)

__global__ __launch_bounds__(256, 2)
void attn_kernel(const unsigned short* __restrict__ Qg,
                 const unsigned short* __restrict__ Kg,
                 const unsigned short* __restrict__ Vt,   // [512][16384] = V^T
                 float* __restrict__ O) {                 // f32 output
  __shared__ unsigned short Ks[32 * 512];   // 32 KB: 32 keys x 512 feats (swizzled)
  __shared__ unsigned short Vs[512 * 32];   // 32 KB: 512 d x 32 keys (swizzled)
  __shared__ float Sx[32][33];              // 4.2 KB
  __shared__ unsigned short Pb[32 * 32];    // 2 KB (XOR-swizzled rows)
  __shared__ float m_row[32], l_row[32], a_row[32];

  const int tid = threadIdx.x;
  const int w = tid >> 6, lane = tid & 63;
  const int quad = lane >> 4, l15 = lane & 15;

  // XCD-contiguous swizzle: 512 blocks, 64 per XCD (bijective)
  const int g0 = blockIdx.x;
  const int g  = (g0 & 7) * 64 + (g0 >> 3);
  const int b  = g >> 7;
  const int q0 = (g & 127) * 32;

  if (tid < 32) { m_row[tid] = -3.0e38f; l_row[tid] = 0.f; }

  const int wq = w >> 1, wk = w & 1;   // phase-1 roles: q-subtile, key-subtile

  // Q A-fragments: 16 q-rows x full K=512 per wave (64 VGPR; R4 pattern)
  bf16x8 qf[16];
  {
    const unsigned short* qrow = Qg + (size_t)(b * 4096 + q0 + wq * 16 + l15) * 512;
#pragma unroll
    for (int i = 0; i < 16; i++)
      qf[i] = *(const bf16x8*)(const void*)(qrow + i * 32 + quad * 8);
  }

  floatx4 oacc[16];   // 2 q-tiles x 8 d-tiles (wave's 128-d slice) = 64 regs
#pragma unroll
  for (int t = 0; t < 16; t++) oacc[t] = (floatx4){0.f, 0.f, 0.f, 0.f};

  const unsigned short* kb0 = Kg + (size_t)b * 4096 * 512;
  const unsigned short* vb0 = Vt + (size_t)b * 4096;

  // K tile stage: 32 rows x 1KB; wave w issue u -> row = w*8+u (row&7 == u).
  // Dest linear; phys chunk p=lane holds logical lane^u (pre-swizzled source).
  auto issue_K = [&](int kt_) {
#pragma unroll
    for (int u = 0; u < 8; u++) {
      const int row = w * 8 + u;
      async_copy16(kb0 + ((size_t)kt_ * 32 + row) * 512 + (lane ^ u) * 8,
                   &Ks[row * 512]);
    }
  };
  // V tile stage: 512 d-rows x 64B; issue unit = 16 rows (1KB).
  // Within unit: row = lane>>2, phys chunk = lane&3; logical = phys ^ (d&3).
  const int v_d4 = lane >> 2;            // row within unit, == d&15; d&3 = v_d4&3
  const int v_sc = (lane & 3) ^ (v_d4 & 3);
  auto issue_V = [&](int kt_) {
#pragma unroll
    for (int u = 0; u < 8; u++) {
      const int unit = w * 8 + u;        // 0..31
      const int d = unit * 16 + v_d4;    // 0..511
      async_copy16(vb0 + (size_t)kt_ * 32 + (size_t)d * 16384 + v_sc * 8,
                   &Vs[unit * 512]);
    }
  };

  const int srow = tid >> 3, sg = tid & 7;
  // Pb write: logical 8B unit sg -> 16B chunk sg>>1 XOR (row&3), half kept
  const int pb_w8 = (((sg >> 1) ^ (srow & 3)) << 1) | (sg & 1);

  issue_K(0);   // prologue: K(0) in flight; published at B1 of kt=0

  for (int kt = 0; kt < 128; kt++) {
    // B1: publish Ks(kt). Explicit per-wave drain (R4-verified pattern).
    asm volatile("s_waitcnt vmcnt(0)" ::: "memory");
    __builtin_amdgcn_sched_barrier(0);
    __syncthreads();
    issue_V(kt);   // Vs dead since last phase 3; flies under phase1+softmax

    // ---- phase 1: one 16x16 S-tile per wave, K=512, 16 MFMA, 2 acc chains
    {
      floatx4 sa = (floatx4){0.f, 0.f, 0.f, 0.f};
      floatx4 sb = (floatx4){0.f, 0.f, 0.f, 0.f};
      const int krow = wk * 16 + l15;    // 0..31
      const int ksw = krow & 7;
#pragma unroll
      for (int i = 0; i < 16; i += 2) {
        bf16x8 k0 = lds_frag(&Ks[krow * 512 + (((i * 4 + quad) ^ ksw) * 8)]);
        sa = mfma_bf16(qf[i], k0, sa);
        bf16x8 k1 = lds_frag(&Ks[krow * 512 + ((((i + 1) * 4 + quad) ^ ksw) * 8)]);
        sb = mfma_bf16(qf[i + 1], k1, sb);
      }
#pragma unroll
      for (int r = 0; r < 4; r++)
        Sx[wq * 16 + quad * 4 + r][wk * 16 + l15] = (sa[r] + sb[r]) * SCALE;
    }
    __syncthreads();        // B2: Sx visible (V DMA still in flight - ok)

    // ---- phase 2: online softmax, 8 lanes x 4 vals per q-row
    {
      float vals[4];
      float tmax = -3.0e38f;
#pragma unroll
      for (int j = 0; j < 4; j++) {
        float xv = Sx[srow][sg * 4 + j];
        xv = fminf(fmaxf(xv, -1.0e4f), 1.0e4f);
        vals[j] = xv;
        tmax = fmaxf(tmax, xv);
      }
      tmax = fmaxf(tmax, __shfl_xor(tmax, 1));
      tmax = fmaxf(tmax, __shfl_xor(tmax, 2));
      tmax = fmaxf(tmax, __shfl_xor(tmax, 4));
      const float m_old = m_row[srow];
      const float m_new = fmaxf(m_old, tmax);
      const float alpha = __expf(m_old - m_new);
      float lsum = 0.f;
      short4v pvec;
#pragma unroll
      for (int j = 0; j < 4; j++) {
        const float p = __expf(vals[j] - m_new);
        lsum += p;
        pvec[j] = (short)f2bf(p);
      }
      lsum += __shfl_xor(lsum, 1);
      lsum += __shfl_xor(lsum, 2);
      lsum += __shfl_xor(lsum, 4);
      *(short4v*)(void*)&Pb[srow * 32 + pb_w8 * 4] = pvec;
      if (sg == 0) {
        m_row[srow] = m_new;
        l_row[srow] = l_row[srow] * alpha + lsum;
        a_row[srow] = alpha;
      }
    }
    __syncthreads();        // B3: Pb, a_row visible (V DMA still in flight - ok)

    // ---- hoisted pre-PV (no Vs access): O-rescale + P A-fragments
    float ar[2][4];
#pragma unroll
    for (int qt = 0; qt < 2; qt++)
#pragma unroll
      for (int r = 0; r < 4; r++) ar[qt][r] = a_row[qt * 16 + quad * 4 + r];
#pragma unroll
    for (int t = 0; t < 16; t++)
#pragma unroll
      for (int r = 0; r < 4; r++) oacc[t][r] *= ar[t >> 3][r];
    bf16x8 pfr[2];
#pragma unroll
    for (int qt = 0; qt < 2; qt++) {
      const int q = qt * 16 + l15;
      pfr[qt] = lds_frag(&Pb[q * 32 + ((quad ^ (l15 & 3)) * 8)]);
    }

    // B4: publish Vs(kt).
    asm volatile("s_waitcnt vmcnt(0)" ::: "memory");
    __builtin_amdgcn_sched_barrier(0);
    __syncthreads();
    if (kt < 127) issue_K(kt + 1);   // Ks dead since B2; flies under phase 3

    // ---- phase 3: O += P V, 16 tiles x 1 MFMA(16x16x32) (K=32 = full tile)
#pragma unroll
    for (int t = 0; t < 16; t++) {
      const int qt = t >> 3, dt = t & 7;
      const int d = w * 128 + dt * 16 + l15;
      bf16x8 vfr = lds_frag(&Vs[d * 32 + ((quad ^ (l15 & 3)) * 8)]);
      oacc[t] = mfma_bf16(pfr[qt], vfr, oacc[t]);
    }
  }

  // ---- epilogue: O / l, f32 store
  __syncthreads();
  float invl[2][4];
#pragma unroll
  for (int qt = 0; qt < 2; qt++)
#pragma unroll
    for (int r = 0; r < 4; r++) invl[qt][r] = 1.0f / l_row[qt * 16 + quad * 4 + r];
#pragma unroll
  for (int t = 0; t < 16; t++) {
    const int qt = t >> 3, dt = t & 7;
#pragma unroll
    for (int r = 0; r < 4; r++) {
      const int row = b * 4096 + q0 + qt * 16 + quad * 4 + r;
      O[(size_t)row * 512 + w * 128 + dt * 16 + l15] = oacc[t][r] * invl[qt][r];
    }
  }
}

// ---- launch ---------------------------------------------------------------
extern "C" void kernel_launch(void* const* d_in, const int* in_sizes, int n_in,
                              void* d_out, int out_size, void* d_ws, size_t ws_size,
                              hipStream_t stream) {
  const float* x   = (const float*)d_in[0];
  const float* wqf = (const float*)d_in[1];
  const float* wkf = (const float*)d_in[2];
  const float* wvf = (const float*)d_in[3];

  unsigned short* Xb  = (unsigned short*)d_out;        // 16384 x 512 bf16 (dead before attn)
  unsigned short* Wqb = (unsigned short*)d_ws;         // 512 x 512
  unsigned short* Wkb = Wqb + (size_t)512 * 512;
  unsigned short* Wvb = Wkb + (size_t)512 * 512;
  unsigned short* Q   = Wvb + (size_t)512 * 512;       // 16384 x 512
  unsigned short* K   = Q + (size_t)16384 * 512;       // 16384 x 512
  unsigned short* Vt  = K + (size_t)16384 * 512;       // 512 x 16384 (V^T)

  prep<<<dim3(8960), 256, 0, stream>>>(x, wqf, wkf, wvf, Xb, Wqb, Wkb, Wvb);
  gemm_qkv<<<dim3(1536), 256, 0, stream>>>(Xb, Wqb, Wkb, Wvb, Q, K, Vt);
  attn_kernel<<<dim3(512), 256, 0, stream>>>(Q, K, Vt, (float*)d_out);
}